// Round 12
// baseline (453.641 us; speedup 1.0000x reference)
//
#include <hip/hip_runtime.h>

// B=4, Cin=Cout=64, H=W=128, K=9, PAD=1. NCHW in/out; NHWC internally for
// the deformable gathers (sample positions are c-invariant, so NHWC makes
// each corner's 64 channels contiguous -> dwordx4 gathers, 2x fewer gather
// instructions, ~8x fewer lines).
#define BAR_LGKM()                                         \
  do {                                                     \
    asm volatile("s_waitcnt lgkmcnt(0)" ::: "memory");     \
    __builtin_amdgcn_s_barrier();                          \
  } while (0)

// XCD-aware swizzle (verified round 4: FETCH 52.6 MB -> 12.7 MB).
__device__ __forceinline__ int swz_block(int bid) {
  return ((bid & 7) << 7) + (bid >> 3);
}

// Workspace layout (floats):
//   wt1   @ 0        (36864)   einsum weights L1 [c][og][k][8]
//   wt2   @ 36864    (36864)
//   wo1   @ 73728    (10368)   offset-conv weights L1 [c][t][18]
//   wo2   @ 84096    (10368)
//   bn1   @ 94464    (128)
//   bn2   @ 94592    (128)
//   offb  @ 94720    (1179648)
//   xT    @ 1274368  (4194304)  x in NHWC [b][hw][c]
//   hbuf  @ 5468672  (4194304)  layer1 out NCHW (for conv_off2)
//   hbufT @ 9662976  (4194304)  layer1 out NHWC (for dcn_main2 gathers)

// ---------------- prep: weight relayouts + BN constants ---------------------
__global__ __launch_bounds__(256) void prep_kernel(
    const float* __restrict__ w1, const float* __restrict__ w2,
    const float* __restrict__ woff1, const float* __restrict__ woff2,
    const float* __restrict__ g1, const float* __restrict__ be1,
    const float* __restrict__ m1, const float* __restrict__ v1,
    const float* __restrict__ g2, const float* __restrict__ be2,
    const float* __restrict__ m2, const float* __restrict__ v2,
    float* __restrict__ ws) {
  float* wt1 = ws;
  float* wt2 = ws + 36864;
  float* wo1 = ws + 73728;
  float* wo2 = ws + 84096;
  float* bn1 = ws + 94464;
  float* bn2 = ws + 94592;
  int idx = blockIdx.x * 256 + threadIdx.x;
  if (idx < 73728) {
    int t = (idx < 36864) ? idx : idx - 36864;
    const float* w = (idx < 36864) ? w1 : w2;
    float* wt = (idx < 36864) ? wt1 : wt2;
    int oi = t & 7;
    int rest = t >> 3;             // (c*8+og)*9 + k
    int k = rest % 9;
    int cog = rest / 9;
    int og = cog & 7, c = cog >> 3;
    int o = og * 8 + oi;
    wt[t] = w[(o * 64 + c) * 9 + k];
  } else if (idx < 94464) {
    int u = idx - 73728;
    int t2 = (u < 10368) ? u : u - 10368;
    const float* w = (u < 10368) ? woff1 : woff2;
    float* wo = (u < 10368) ? wo1 : wo2;
    int j = t2 % 18;
    int v = t2 / 18;               // c*9 + t
    int tt = v % 9;
    int c = v / 9;
    wo[t2] = w[(j * 64 + c) * 9 + tt];
  } else if (idx < 94528) {
    int o = idx - 94464;
    float s = g1[o] * rsqrtf(v1[o] + 1e-5f);
    bn1[o] = s;
    bn1[64 + o] = be1[o] - m1[o] * s;
  } else if (idx < 94592) {
    int o = idx - 94528;
    float s = g2[o] * rsqrtf(v2[o] + 1e-5f);
    bn2[o] = s;
    bn2[64 + o] = be2[o] - m2[o] * s;
  }
}

// ---------------- transpose: NCHW -> NHWC ----------------------------------
// 1024 blocks x 256 threads: 64hw x 64c tile via LDS; coalesced both sides.
__global__ __launch_bounds__(256) void transpose_kernel(
    const float* __restrict__ in, float* __restrict__ outT) {
  __shared__ float t[64][65];
  int bid = blockIdx.x;
  int b = bid >> 8;
  int hw0 = (bid & 255) << 6;
  int px = threadIdx.x & 63, cg = threadIdx.x >> 6;   // cg 0..3
  const float* ib = in + ((size_t)b << 20) + hw0 + px;
#pragma unroll
  for (int i = 0; i < 16; ++i) {
    int c = cg * 16 + i;
    t[px][c] = ib[(size_t)c << 14];
  }
  __syncthreads();
  int hw = threadIdx.x >> 2, c0 = (threadIdx.x & 3) << 4;
  float* ob = outT + ((size_t)b << 20) + (size_t)(hw0 + hw) * 64 + c0;
#pragma unroll
  for (int i = 0; i < 4; ++i) {
    float4 v = make_float4(t[hw][c0 + i * 4], t[hw][c0 + i * 4 + 1],
                           t[hw][c0 + i * 4 + 2], t[hw][c0 + i * 4 + 3]);
    *(float4*)(ob + i * 4) = v;
  }
}

// ---------------- offset conv: 3x3, 64 -> 18 ch, zero pad -------------------
// Single-stage variant: the whole 64c x 3row x 66px halo (50.7 KB) staged
// ONCE, one barrier total (vs 16 barrier-phases) -> tests whether conv_off's
// ~65us wall is its iteration/barrier structure.
__global__ __launch_bounds__(512, 4) void conv_off_kernel(
    const float* __restrict__ xin, const float* __restrict__ wofft,
    const float* __restrict__ boff, float* __restrict__ off) {
  __shared__ float hb[12672];      // [c][r*66+cc], stride 198
  int tid = threadIdx.x;
  int pxl = tid & 63;
  int og = tid >> 6;
  int ogu = __builtin_amdgcn_readfirstlane(og);
  int p0 = swz_block(blockIdx.x) * 64;
  int b = p0 >> 14, hw0 = p0 & 16383;
  int h = hw0 >> 7, w0 = hw0 & 127;
  const float* xb0 = xin + ((size_t)(b * 64) << 14);

#pragma unroll 1
  for (int e = tid; e < 12672; e += 512) {
    int c = e / 198;
    int pos = e - c * 198;
    int r = pos / 66;
    int cc = pos - r * 66;
    int yy = h + r - 1, xx = w0 + cc - 1;
    bool inb = (yy >= 0) && (yy < 128) && (xx >= 0) && (xx < 128);
    hb[e] = inb ? xb0[((size_t)c << 14) + (yy << 7) + xx] : 0.f;
  }
  __syncthreads();

  int jbase = (ogu < 2) ? ogu * 3 : 6 + (ogu - 2) * 2;
  int nj = (ogu < 2) ? 3 : 2;
  int jc2 = jbase + 2;
  if (jc2 > 17) jc2 = 17;

  float acc[3] = {0.f, 0.f, 0.f};
#pragma unroll 1
  for (int c = 0; c < 64; ++c) {
    const float* wc = wofft + c * 162;
    const float* base = hb + c * 198;
#pragma unroll
    for (int t = 0; t < 9; ++t) {
      float v = base[(t / 3) * 66 + pxl + (t % 3)];
      acc[0] = fmaf(v, wc[t * 18 + jbase], acc[0]);
      acc[1] = fmaf(v, wc[t * 18 + jbase + 1], acc[1]);
      acc[2] = fmaf(v, wc[t * 18 + jc2], acc[2]);
    }
  }
#pragma unroll
  for (int i = 0; i < 3; ++i) {
    if (i < nj) {
      int j = jbase + i;
      off[((size_t)(b * 18 + j) << 14) + hw0 + pxl] = acc[i] + boff[j];
    }
  }
}

// ---------------- fused deformable sample + einsum + BN + ReLU --------------
// NHWC gathers: per slot 4 corner streams; each 4-channel chunk = 4 dwordx4
// loads (vs 16 float2 in NCHW -> 2x fewer gather instrs, the proven lever).
// 16 chunks of 4c; R7 flow per chunk: blend -> LDS -> prefetch -> lgkm
// barrier -> VALU einsum (s_load weights). (512,4): VGPR cap 128, no spill.
__global__ __launch_bounds__(512, 4) void dcn_main_kernel(
    const float* __restrict__ xT, const float* __restrict__ off,
    const float* __restrict__ wt, const float* __restrict__ bn,
    float* __restrict__ out, float* __restrict__ outT) {
  __shared__ float sbuf[2][4][576];   // [buf][ci][k*64+px]
  int tid = threadIdx.x;
  int pxl = tid & 63;
  int og = tid >> 6;
  int ogu = __builtin_amdgcn_readfirstlane(og);
  int p0 = swz_block(blockIdx.x) * 64;
  int b = p0 >> 14, hw0 = p0 & 16383;
  int h = hw0 >> 7, w0 = hw0 & 127;
  const float* xbT = xT + ((size_t)b << 20);

  bool act1 = (tid & 7) == 0;      // slot1 (k=8) handled by 1/8 of threads
  int s1 = 512 + (tid >> 3);

  float q[2][4];
  const float* cp[2][4];           // corner base pointers (c=0)

#pragma unroll
  for (int j = 0; j < 2; ++j) {
    bool a = (j == 0) || act1;
    int s = (j == 0) ? tid : s1;
    int k = s >> 6;
    if (k > 8) k = 8;
    int pxs = s & 63;
    int hw = hw0 + pxs;
    float dy = a ? off[((size_t)(b * 18 + 2 * k) << 14) + hw] : 0.f;
    float dx = a ? off[((size_t)(b * 18 + 2 * k + 1) << 14) + hw] : 0.f;
    float py = (float)(h + k / 3 - 1) + dy;
    float pxf = (float)(w0 + pxs + k % 3 - 1) + dx;
    float y0f = floorf(py), x0f = floorf(pxf);
    float wy1 = py - y0f, wx1 = pxf - x0f;
    float wy0 = 1.f - wy1, wx0 = 1.f - wx1;
    int y0 = (int)y0f, x0 = (int)x0f;
    int y1 = y0 + 1, x1 = x0 + 1;
    bool vy0 = (y0 >= 0) && (y0 <= 127);
    bool vy1 = (y1 >= 0) && (y1 <= 127);
    bool vx0 = (x0 >= 0) && (x0 <= 127);
    bool vx1 = (x1 >= 0) && (x1 <= 127);
    q[j][0] = (vy0 && vx0) ? wy0 * wx0 : 0.f;
    q[j][1] = (vy0 && vx1) ? wy0 * wx1 : 0.f;
    q[j][2] = (vy1 && vx0) ? wy1 * wx0 : 0.f;
    q[j][3] = (vy1 && vx1) ? wy1 * wx1 : 0.f;
    int y0c = min(max(y0, 0), 127), y1c = min(max(y1, 0), 127);
    int x0c = min(max(x0, 0), 127), x1c = min(max(x1, 0), 127);
    cp[j][0] = xbT + ((size_t)((y0c << 7) + x0c) << 6);
    cp[j][1] = xbT + ((size_t)((y0c << 7) + x1c) << 6);
    cp[j][2] = xbT + ((size_t)((y1c << 7) + x0c) << 6);
    cp[j][3] = xbT + ((size_t)((y1c << 7) + x1c) << 6);
  }

  // prologue: taps for chunk 0
  float4 tA[4], tB[4];
#pragma unroll
  for (int ci = 0; ci < 4; ++ci) tA[ci] = *(const float4*)(cp[0][ci]);
#pragma unroll
  for (int ci = 0; ci < 4; ++ci)
    tB[ci] = act1 ? *(const float4*)(cp[1][ci]) : make_float4(0, 0, 0, 0);

  float acc[8];
#pragma unroll
  for (int oi = 0; oi < 8; ++oi) acc[oi] = 0.f;

#pragma unroll 1
  for (int cc = 0; cc < 16; ++cc) {
    int buf = cc & 1;
    // blend 4 channels (float4 lanes) -> sbuf
    {
      float sx = fmaf(q[0][0], tA[0].x, fmaf(q[0][1], tA[1].x,
                 fmaf(q[0][2], tA[2].x, q[0][3] * tA[3].x)));
      float sy = fmaf(q[0][0], tA[0].y, fmaf(q[0][1], tA[1].y,
                 fmaf(q[0][2], tA[2].y, q[0][3] * tA[3].y)));
      float sz = fmaf(q[0][0], tA[0].z, fmaf(q[0][1], tA[1].z,
                 fmaf(q[0][2], tA[2].z, q[0][3] * tA[3].z)));
      float sw = fmaf(q[0][0], tA[0].w, fmaf(q[0][1], tA[1].w,
                 fmaf(q[0][2], tA[2].w, q[0][3] * tA[3].w)));
      sbuf[buf][0][tid] = sx;
      sbuf[buf][1][tid] = sy;
      sbuf[buf][2][tid] = sz;
      sbuf[buf][3][tid] = sw;
    }
    if (act1) {
      float sx = fmaf(q[1][0], tB[0].x, fmaf(q[1][1], tB[1].x,
                 fmaf(q[1][2], tB[2].x, q[1][3] * tB[3].x)));
      float sy = fmaf(q[1][0], tB[0].y, fmaf(q[1][1], tB[1].y,
                 fmaf(q[1][2], tB[2].y, q[1][3] * tB[3].y)));
      float sz = fmaf(q[1][0], tB[0].z, fmaf(q[1][1], tB[1].z,
                 fmaf(q[1][2], tB[2].z, q[1][3] * tB[3].z)));
      float sw = fmaf(q[1][0], tB[0].w, fmaf(q[1][1], tB[1].w,
                 fmaf(q[1][2], tB[2].w, q[1][3] * tB[3].w)));
      sbuf[buf][0][s1] = sx;
      sbuf[buf][1][s1] = sy;
      sbuf[buf][2][s1] = sz;
      sbuf[buf][3][s1] = sw;
    }
    // prefetch next chunk's taps (in flight across the lgkm barrier)
    if (cc < 15) {
      int d = (cc + 1) << 2;
#pragma unroll
      for (int ci = 0; ci < 4; ++ci) tA[ci] = *(const float4*)(cp[0][ci] + d);
      if (act1) {
#pragma unroll
        for (int ci = 0; ci < 4; ++ci) tB[ci] = *(const float4*)(cp[1][ci] + d);
      }
    }
    BAR_LGKM();
    // einsum over the 4 staged channels (s_load weights, R7 path)
#pragma unroll
    for (int i = 0; i < 4; ++i) {
      const float* wc = wt + (((cc << 2) + i) * 8 + ogu) * 72;
#pragma unroll
      for (int k = 0; k < 9; ++k) {
        float sval = sbuf[buf][i][k * 64 + pxl];
#pragma unroll
        for (int oi = 0; oi < 8; ++oi)
          acc[oi] = fmaf(sval, wc[k * 8 + oi], acc[oi]);
      }
    }
  }

  float rr[8];
#pragma unroll
  for (int oi = 0; oi < 8; ++oi) {
    int o = ogu * 8 + oi;
    float r = fmaxf(fmaf(acc[oi], bn[o], bn[64 + o]), 0.f);
    rr[oi] = r;
    out[((size_t)(b * 64 + o) << 14) + hw0 + pxl] = r;
  }
  if (outT) {
    float* ob = outT + ((size_t)b << 20) + (size_t)(hw0 + pxl) * 64 + ogu * 8;
    *(float4*)ob = make_float4(rr[0], rr[1], rr[2], rr[3]);
    *(float4*)(ob + 4) = make_float4(rr[4], rr[5], rr[6], rr[7]);
  }
}

extern "C" void kernel_launch(void* const* d_in, const int* in_sizes, int n_in,
                              void* d_out, int out_size, void* d_ws, size_t ws_size,
                              hipStream_t stream) {
  const float* x      = (const float*)d_in[0];
  const float* w_off1 = (const float*)d_in[1];
  const float* b_off1 = (const float*)d_in[2];
  const float* w1     = (const float*)d_in[3];
  const float* g1     = (const float*)d_in[4];
  const float* be1    = (const float*)d_in[5];
  const float* m1     = (const float*)d_in[6];
  const float* v1     = (const float*)d_in[7];
  const float* w_off2 = (const float*)d_in[8];
  const float* b_off2 = (const float*)d_in[9];
  const float* w2     = (const float*)d_in[10];
  const float* g2     = (const float*)d_in[11];
  const float* be2    = (const float*)d_in[12];
  const float* m2     = (const float*)d_in[13];
  const float* v2     = (const float*)d_in[14];
  float* out = (float*)d_out;

  float* ws    = (float*)d_ws;
  float* wt1   = ws;
  float* wt2   = ws + 36864;
  float* wo1   = ws + 73728;
  float* wo2   = ws + 84096;
  float* bn1   = ws + 94464;
  float* bn2   = ws + 94592;
  float* offb  = ws + 94720;
  float* xT    = ws + 1274368;
  float* hbuf  = ws + 5468672;
  float* hbufT = ws + 9662976;

  prep_kernel<<<370, 256, 0, stream>>>(w1, w2, w_off1, w_off2,
                                       g1, be1, m1, v1, g2, be2, m2, v2, ws);
  transpose_kernel<<<1024, 256, 0, stream>>>(x, xT);

  conv_off_kernel<<<1024, 512, 0, stream>>>(x, wo1, b_off1, offb);
  dcn_main_kernel<<<1024, 512, 0, stream>>>(xT, offb, wt1, bn1, hbuf, hbufT);

  conv_off_kernel<<<1024, 512, 0, stream>>>(hbuf, wo2, b_off2, offb);
  dcn_main_kernel<<<1024, 512, 0, stream>>>(hbufT, offb, wt2, bn2, out, nullptr);
}

// Round 13
// 335.837 us; speedup vs baseline: 1.3508x; 1.3508x over previous
//
#include <hip/hip_runtime.h>

// B=4, Cin=Cout=64, H=W=128, K=9, PAD=1. NCHW fp32.
//
// lgkm-only barrier: LDS producer->consumer needs lgkmcnt(0) only; global
// prefetch loads stay in flight across it (vmcnt wait lands at the use).
#define BAR_LGKM()                                         \
  do {                                                     \
    asm volatile("s_waitcnt lgkmcnt(0)" ::: "memory");     \
    __builtin_amdgcn_s_barrier();                          \
  } while (0)

// XCD-aware swizzle (verified round 4: FETCH 52.6 MB -> 12.7 MB).
__device__ __forceinline__ int swz_block(int bid) {
  return ((bid & 7) << 7) + (bid >> 3);
}

// Workspace layout (floats):
//   wt1  @ 0       (36864)  main weights layer1, [c][og][k][oi] (og=o/8, oi=o%8)
//   wt2  @ 36864   (36864)
//   wo1  @ 73728   (10368)  offset-conv weights layer1, [c][t][j] (j=0..17)
//   wo2  @ 84096   (10368)
//   bn1  @ 94464   (128)    scale[64], shift[64]
//   bn2  @ 94592   (128)
//   offb @ 94720   (1179648)  4*18*16384
//   hbuf @ 1274368 (4194304)  4*64*16384

// ---------------- prep: weight relayouts + BN constants ---------------------
__global__ __launch_bounds__(256) void prep_kernel(
    const float* __restrict__ w1, const float* __restrict__ w2,
    const float* __restrict__ woff1, const float* __restrict__ woff2,
    const float* __restrict__ g1, const float* __restrict__ be1,
    const float* __restrict__ m1, const float* __restrict__ v1,
    const float* __restrict__ g2, const float* __restrict__ be2,
    const float* __restrict__ m2, const float* __restrict__ v2,
    float* __restrict__ ws) {
  float* wt1 = ws;
  float* wt2 = ws + 36864;
  float* wo1 = ws + 73728;
  float* wo2 = ws + 84096;
  float* bn1 = ws + 94464;
  float* bn2 = ws + 94592;
  int idx = blockIdx.x * 256 + threadIdx.x;
  if (idx < 73728) {
    int t = (idx < 36864) ? idx : idx - 36864;
    const float* w = (idx < 36864) ? w1 : w2;
    float* wt = (idx < 36864) ? wt1 : wt2;
    int oi = t & 7;
    int rest = t >> 3;             // (c*8+og)*9 + k
    int k = rest % 9;
    int cog = rest / 9;
    int og = cog & 7, c = cog >> 3;
    int o = og * 8 + oi;
    wt[t] = w[(o * 64 + c) * 9 + k];
  } else if (idx < 94464) {
    int u = idx - 73728;
    int t2 = (u < 10368) ? u : u - 10368;
    const float* w = (u < 10368) ? woff1 : woff2;
    float* wo = (u < 10368) ? wo1 : wo2;
    int j = t2 % 18;
    int v = t2 / 18;               // c*9 + t
    int tt = v % 9;
    int c = v / 9;
    wo[t2] = w[(j * 64 + c) * 9 + tt];
  } else if (idx < 94528) {
    int o = idx - 94464;
    float s = g1[o] * rsqrtf(v1[o] + 1e-5f);
    bn1[o] = s;
    bn1[64 + o] = be1[o] - m1[o] * s;
  } else if (idx < 94592) {
    int o = idx - 94528;
    float s = g2[o] * rsqrtf(v2[o] + 1e-5f);
    bn2[o] = s;
    bn2[64 + o] = be2[o] - m2[o] * s;
  }
}

// ---------------- offset conv: 3x3, 64 -> 18 ch, zero pad -------------------
// (round-4 version — best measured ~65us; single-stage variant regressed)
__global__ __launch_bounds__(512, 8) void conv_off_kernel(
    const float* __restrict__ xin, const float* __restrict__ wofft,
    const float* __restrict__ boff, float* __restrict__ off) {
  __shared__ float halo[2][792];   // [buf][plane*198 + pos], 4 planes/stage
  int tid = threadIdx.x;
  int pxl = tid & 63;
  int og = tid >> 6;
  int ogu = __builtin_amdgcn_readfirstlane(og);
  int p0 = swz_block(blockIdx.x) * 64;
  int b = p0 >> 14, hw0 = p0 & 16383;
  int h = hw0 >> 7, w0 = hw0 & 127;

  bool sv = tid < 396;
  int pp = (tid >= 198) ? 1 : 0;
  int pos = tid - pp * 198;
  int r = pos / 66, cc = pos - r * 66;
  int yy = h + r - 1, xx = w0 + cc - 1;
  bool inb = sv && (yy >= 0) && (yy < 128) && (xx >= 0) && (xx < 128);
  int ofs = (yy << 7) + xx;
  const float* xb0 = xin + ((size_t)(b * 64) << 14);

  float stg0 = inb ? xb0[((size_t)pp << 14) + ofs] : 0.f;
  float stg1 = inb ? xb0[((size_t)(2 + pp) << 14) + ofs] : 0.f;

  int jbase = (ogu < 2) ? ogu * 3 : 6 + (ogu - 2) * 2;
  int nj = (ogu < 2) ? 3 : 2;
  int jc2 = jbase + 2;
  if (jc2 > 17) jc2 = 17;

  float acc[3] = {0.f, 0.f, 0.f};

#pragma unroll 1
  for (int cg = 0; cg < 64; cg += 4) {
    int bufi = (cg >> 2) & 1;
    if (sv) {
      halo[bufi][pp * 198 + pos] = stg0;
      halo[bufi][(2 + pp) * 198 + pos] = stg1;
    }
    if (cg < 60) {
      stg0 = inb ? xb0[((size_t)(cg + 4 + pp) << 14) + ofs] : 0.f;
      stg1 = inb ? xb0[((size_t)(cg + 6 + pp) << 14) + ofs] : 0.f;
    }
    BAR_LGKM();
    const float* hb = halo[bufi];
#pragma unroll
    for (int p = 0; p < 4; ++p) {
      const float* wc = wofft + (cg + p) * 162;
#pragma unroll
      for (int t = 0; t < 9; ++t) {
        float v = hb[p * 198 + (t / 3) * 66 + pxl + (t % 3)];
        acc[0] = fmaf(v, wc[t * 18 + jbase], acc[0]);
        acc[1] = fmaf(v, wc[t * 18 + jbase + 1], acc[1]);
        acc[2] = fmaf(v, wc[t * 18 + jc2], acc[2]);
      }
    }
  }
#pragma unroll
  for (int i = 0; i < 3; ++i) {
    if (i < nj) {
      int j = jbase + i;
      off[((size_t)(b * 18 + j) << 14) + hw0 + pxl] = acc[i] + boff[j];
    }
  }
}

// ---------------- fused deformable sample + einsum + BN + ReLU --------------
// R7 structure + y-SORTED slot assignment. TA model (fits all 13 rounds):
// cost = gather instrs x lines/instr. Sample positions are c-invariant, so
// counting-sort the 576 slots by y0 once (21 LDS buckets); a wave's 64
// lanes then hold y-adjacent slots -> gathers span ~2 rows instead of ~8
// (~15 lines/instr vs ~40). Blend results scatter to sbuf[orig_slot], so
// the einsum is unchanged and results are bit-exact.
__global__ __launch_bounds__(512, 8) void dcn_main_kernel(
    const float* __restrict__ xin, const float* __restrict__ off,
    const float* __restrict__ wt, const float* __restrict__ bn,
    float* __restrict__ out) {
  __shared__ float prm[576 * 6];   // per-slot {q0,q1,q2,q3, ra, rb}
  __shared__ int sortmap[576];
  __shared__ int hist[32];
  __shared__ float sbuf[2][576];
  int tid = threadIdx.x;
  int pxl = tid & 63;
  int og = tid >> 6;
  int ogu = __builtin_amdgcn_readfirstlane(og);
  int p0 = swz_block(blockIdx.x) * 64;
  int b = p0 >> 14, hw0 = p0 & 16383;
  int h = hw0 >> 7, w0 = hw0 & 127;
  const float* xb = xin + ((size_t)b << 20);

  bool act1 = (tid & 7) == 0;      // this thread also owns slot s1
  int s1 = 512 + (tid >> 3);

  if (tid < 32) hist[tid] = 0;

  // ---- compute per-slot params (R7 folded-coeff path), store to LDS ----
  int bkt[2];
#pragma unroll
  for (int j = 0; j < 2; ++j) {
    bool a = (j == 0) || act1;
    int s = (j == 0) ? tid : s1;
    int k = s >> 6;                // 0..8
    int pxs = s & 63;
    int hw = hw0 + pxs;
    float dy = a ? off[((size_t)(b * 18 + 2 * k) << 14) + hw] : 0.f;
    float dx = a ? off[((size_t)(b * 18 + 2 * k + 1) << 14) + hw] : 0.f;
    float py = (float)(h + k / 3 - 1) + dy;
    float pxf = (float)(w0 + pxs + k % 3 - 1) + dx;
    float y0f = floorf(py), x0f = floorf(pxf);
    float wy1 = py - y0f, wx1 = pxf - x0f;
    float wy0 = 1.f - wy1, wx0 = 1.f - wx1;
    int y0 = (int)y0f, x0 = (int)x0f;
    int y1 = y0 + 1, x1 = x0 + 1;
    bool vy0 = (y0 >= 0) && (y0 <= 127);
    bool vy1 = (y1 >= 0) && (y1 <= 127);
    bool vx0 = (x0 >= 0) && (x0 <= 127);
    bool vx1 = (x1 >= 0) && (x1 <= 127);
    float pw0 = (vy0 && vx0) ? wy0 * wx0 : 0.f;
    float pw1 = (vy0 && vx1) ? wy0 * wx1 : 0.f;
    float pw2 = (vy1 && vx0) ? wy1 * wx0 : 0.f;
    float pw3 = (vy1 && vx1) ? wy1 * wx1 : 0.f;
    int y0c = min(max(y0, 0), 127), y1c = min(max(y1, 0), 127);
    int xb2 = min(max(x0, 0), 126);
    bool se0 = (x0 == xb2);
    bool se1 = (x0 + 1 == xb2);
    // folded coeffs on the clamped float2 pair base (exact: the "wrong"
    // select's pw is already 0)
    float f0 = (se0 ? pw0 : 0.f) + (se1 ? pw1 : 0.f);
    float f1 = (se0 ? 0.f : pw0) + (se1 ? 0.f : pw1);
    float f2 = (se0 ? pw2 : 0.f) + (se1 ? pw3 : 0.f);
    float f3 = (se0 ? 0.f : pw2) + (se1 ? 0.f : pw3);
    if (a) {
      float* pp = &prm[s * 6];
      pp[0] = f0; pp[1] = f1; pp[2] = f2; pp[3] = f3;
      ((int*)pp)[4] = (y0c << 7) + xb2;
      ((int*)pp)[5] = (y1c << 7) + xb2;
    }
    bkt[j] = min(max(y0 - (h - 10), 0), 20);
  }
  __syncthreads();
  // ---- counting sort by y-bucket ----
  atomicAdd(&hist[bkt[0]], 1);
  if (act1) atomicAdd(&hist[bkt[1]], 1);
  __syncthreads();
  if (tid == 0) {
    int run = 0;
#pragma unroll 1
    for (int i = 0; i <= 20; ++i) { int t = hist[i]; hist[i] = run; run += t; }
  }
  __syncthreads();
  {
    int r0 = atomicAdd(&hist[bkt[0]], 1);
    sortmap[r0] = tid;
    if (act1) {
      int r1 = atomicAdd(&hist[bkt[1]], 1);
      sortmap[r1] = s1;
    }
  }
  __syncthreads();

  // ---- load working params for sorted slots ----
  int ws0 = sortmap[tid];
  int ws1 = act1 ? sortmap[512 + (tid >> 3)] : 0;
  float q[2][4];
  const float* pa[2];
  const float* pb[2];
  {
    const float* pp = &prm[ws0 * 6];
    q[0][0] = pp[0]; q[0][1] = pp[1]; q[0][2] = pp[2]; q[0][3] = pp[3];
    pa[0] = xb + ((const int*)pp)[4];
    pb[0] = xb + ((const int*)pp)[5];
  }
  if (act1) {
    const float* pp = &prm[ws1 * 6];
    q[1][0] = pp[0]; q[1][1] = pp[1]; q[1][2] = pp[2]; q[1][3] = pp[3];
    pa[1] = xb + ((const int*)pp)[4];
    pb[1] = xb + ((const int*)pp)[5];
  } else {
    q[1][0] = q[1][1] = q[1][2] = q[1][3] = 0.f;
    pa[1] = xb; pb[1] = xb;
  }

  // prologue: taps for c=0; advance pointers to plane 1
  float2 t0a = *(const float2*)pa[0];
  float2 t1a = *(const float2*)pb[0];
  float2 t0b = act1 ? *(const float2*)pa[1] : make_float2(0.f, 0.f);
  float2 t1b = act1 ? *(const float2*)pb[1] : make_float2(0.f, 0.f);
  pa[0] += 16384; pb[0] += 16384; pa[1] += 16384; pb[1] += 16384;

  float acc[8];
#pragma unroll
  for (int oi = 0; oi < 8; ++oi) acc[oi] = 0.f;

#pragma unroll 1
  for (int c = 0; c < 64; ++c) {
    // blend + scatter to sbuf at the ORIGINAL slot ids (einsum unchanged)
    sbuf[c & 1][ws0] = fmaf(q[0][0], t0a.x,
                       fmaf(q[0][1], t0a.y,
                       fmaf(q[0][2], t1a.x, q[0][3] * t1a.y)));
    if (act1) {
      sbuf[c & 1][ws1] = fmaf(q[1][0], t0b.x,
                         fmaf(q[1][1], t0b.y,
                         fmaf(q[1][2], t1b.x, q[1][3] * t1b.y)));
    }
    // prefetch taps for c+1 (in flight across the lgkm barrier)
    if (c < 63) {
      t0a = *(const float2*)pa[0];
      t1a = *(const float2*)pb[0];
      if (act1) {
        t0b = *(const float2*)pa[1];
        t1b = *(const float2*)pb[1];
      }
      pa[0] += 16384; pb[0] += 16384; pa[1] += 16384; pb[1] += 16384;
    }
    BAR_LGKM();
    const float* wc = wt + (c * 8 + ogu) * 72;   // [c][og][k][8], s_load
#pragma unroll
    for (int k = 0; k < 9; ++k) {
      float sval = sbuf[c & 1][k * 64 + pxl];
#pragma unroll
      for (int oi = 0; oi < 8; ++oi)
        acc[oi] = fmaf(sval, wc[k * 8 + oi], acc[oi]);
    }
  }

#pragma unroll
  for (int oi = 0; oi < 8; ++oi) {
    int o = ogu * 8 + oi;
    float rres = fmaf(acc[oi], bn[o], bn[64 + o]);
    out[((size_t)(b * 64 + o) << 14) + hw0 + pxl] = fmaxf(rres, 0.f);
  }
}

extern "C" void kernel_launch(void* const* d_in, const int* in_sizes, int n_in,
                              void* d_out, int out_size, void* d_ws, size_t ws_size,
                              hipStream_t stream) {
  const float* x      = (const float*)d_in[0];
  const float* w_off1 = (const float*)d_in[1];
  const float* b_off1 = (const float*)d_in[2];
  const float* w1     = (const float*)d_in[3];
  const float* g1     = (const float*)d_in[4];
  const float* be1    = (const float*)d_in[5];
  const float* m1     = (const float*)d_in[6];
  const float* v1     = (const float*)d_in[7];
  const float* w_off2 = (const float*)d_in[8];
  const float* b_off2 = (const float*)d_in[9];
  const float* w2     = (const float*)d_in[10];
  const float* g2     = (const float*)d_in[11];
  const float* be2    = (const float*)d_in[12];
  const float* m2     = (const float*)d_in[13];
  const float* v2     = (const float*)d_in[14];
  float* out = (float*)d_out;

  float* ws   = (float*)d_ws;
  float* wt1  = ws;
  float* wt2  = ws + 36864;
  float* wo1  = ws + 73728;
  float* wo2  = ws + 84096;
  float* bn1  = ws + 94464;
  float* bn2  = ws + 94592;
  float* offb = ws + 94720;
  float* hbuf = ws + 1274368;

  prep_kernel<<<370, 256, 0, stream>>>(w1, w2, w_off1, w_off2,
                                       g1, be1, m1, v1, g2, be2, m2, v2, ws);

  conv_off_kernel<<<1024, 512, 0, stream>>>(x, wo1, b_off1, offb);
  dcn_main_kernel<<<1024, 512, 0, stream>>>(x, offb, wt1, bn1, hbuf);

  conv_off_kernel<<<1024, 512, 0, stream>>>(hbuf, wo2, b_off2, offb);
  dcn_main_kernel<<<1024, 512, 0, stream>>>(hbuf, offb, wt2, bn2, out);
}

// Round 14
// 327.789 us; speedup vs baseline: 1.3839x; 1.0246x over previous
//
#include <hip/hip_runtime.h>

// B=4, Cin=Cout=64, H=W=128, K=9, PAD=1. NCHW fp32.
//
// lgkm-only barrier: LDS producer->consumer needs lgkmcnt(0) only; global
// prefetch loads stay in flight across it (vmcnt wait lands at the use).
#define BAR_LGKM()                                         \
  do {                                                     \
    asm volatile("s_waitcnt lgkmcnt(0)" ::: "memory");     \
    __builtin_amdgcn_s_barrier();                          \
  } while (0)

// XCD-aware swizzle (verified round 4: FETCH 52.6 MB -> 12.7 MB).
__device__ __forceinline__ int swz_block(int bid) {
  return ((bid & 7) << 7) + (bid >> 3);
}

// Workspace layout (floats):
//   wt1  @ 0       (36864)  main weights layer1, [c][og][k][oi] (og=o/8, oi=o%8)
//   wt2  @ 36864   (36864)
//   wo1  @ 73728   (10368)  offset-conv weights layer1, [c][t][j] (j=0..17)
//   wo2  @ 84096   (10368)
//   bn1  @ 94464   (128)    scale[64], shift[64]
//   bn2  @ 94592   (128)
//   offb @ 94720   (1179648)  4*18*16384
//   hbuf @ 1274368 (4194304)  4*64*16384

// ---------------- prep: weight relayouts + BN constants ---------------------
__global__ __launch_bounds__(256) void prep_kernel(
    const float* __restrict__ w1, const float* __restrict__ w2,
    const float* __restrict__ woff1, const float* __restrict__ woff2,
    const float* __restrict__ g1, const float* __restrict__ be1,
    const float* __restrict__ m1, const float* __restrict__ v1,
    const float* __restrict__ g2, const float* __restrict__ be2,
    const float* __restrict__ m2, const float* __restrict__ v2,
    float* __restrict__ ws) {
  float* wt1 = ws;
  float* wt2 = ws + 36864;
  float* wo1 = ws + 73728;
  float* wo2 = ws + 84096;
  float* bn1 = ws + 94464;
  float* bn2 = ws + 94592;
  int idx = blockIdx.x * 256 + threadIdx.x;
  if (idx < 73728) {
    int t = (idx < 36864) ? idx : idx - 36864;
    const float* w = (idx < 36864) ? w1 : w2;
    float* wt = (idx < 36864) ? wt1 : wt2;
    int oi = t & 7;
    int rest = t >> 3;             // (c*8+og)*9 + k
    int k = rest % 9;
    int cog = rest / 9;
    int og = cog & 7, c = cog >> 3;
    int o = og * 8 + oi;
    wt[t] = w[(o * 64 + c) * 9 + k];
  } else if (idx < 94464) {
    int u = idx - 73728;
    int t2 = (u < 10368) ? u : u - 10368;
    const float* w = (u < 10368) ? woff1 : woff2;
    float* wo = (u < 10368) ? wo1 : wo2;
    int j = t2 % 18;
    int v = t2 / 18;               // c*9 + t
    int tt = v % 9;
    int c = v / 9;
    wo[t2] = w[(j * 64 + c) * 9 + tt];
  } else if (idx < 94528) {
    int o = idx - 94464;
    float s = g1[o] * rsqrtf(v1[o] + 1e-5f);
    bn1[o] = s;
    bn1[64 + o] = be1[o] - m1[o] * s;
  } else if (idx < 94592) {
    int o = idx - 94528;
    float s = g2[o] * rsqrtf(v2[o] + 1e-5f);
    bn2[o] = s;
    bn2[64 + o] = be2[o] - m2[o] * s;
  }
}

// ---------------- offset conv: 3x3, 64 -> 18 ch, zero pad -------------------
// Restructured 128px x 4og (512 blocks, one full image row per block).
// Old 64px x 8og had every halo value read by 8 og-waves (LDS-read pipe was
// 6700 of its ~9750 cyc/phase wall). 4og halves the per-pixel LDS-read
// redundancy; j-split 5/5/4/4. Same 4-plane dbuf staging + lgkm barrier.
__global__ __launch_bounds__(512, 8) void conv_off_kernel(
    const float* __restrict__ xin, const float* __restrict__ wofft,
    const float* __restrict__ boff, float* __restrict__ off) {
  __shared__ float halo[2][1560];   // [buf][p*390 + r*130 + cc]
  int tid = threadIdx.x;
  int px = tid & 127;
  int og = tid >> 7;               // 0..3
  int ogu = __builtin_amdgcn_readfirstlane(og);
  // 512 blocks, 8 XCDs, bijective: XCD k gets 64 consecutive rows (matches
  // dcn's region->XCD mapping so layer-1 writes are L2-warm for layer 2).
  int rid = ((blockIdx.x & 7) << 6) + (blockIdx.x >> 3);
  int b = rid >> 7, h = rid & 127;
  const float* xb0 = xin + ((size_t)(b * 64) << 14);

  int sofs[4]; int spl[4]; bool svld[4], sok[4];
#pragma unroll
  for (int i = 0; i < 4; ++i) {
    int e = tid + (i << 9);
    bool ok = e < 1560;
    int ec = ok ? e : 0;
    int p = ec / 390;
    int rr = ec - p * 390;
    int r = rr / 130;
    int cc = rr - r * 130;
    int y = h + r - 1, xx = cc - 1;
    sok[i] = ok;
    svld[i] = ok && (y >= 0) && (y < 128) && (xx >= 0) && (xx < 128);
    sofs[i] = (y << 7) + xx;
    spl[i] = p;
  }

  // prologue: planes 0..3
  float stg[4];
#pragma unroll
  for (int i = 0; i < 4; ++i)
    stg[i] = svld[i] ? xb0[((size_t)spl[i] << 14) + sofs[i]] : 0.f;

  int jbase = (ogu < 2) ? ogu * 5 : 10 + (ogu - 2) * 4;
  int nj = (ogu < 2) ? 5 : 4;
  int j4 = jbase + 4;
  if (j4 > 17) j4 = 17;            // clamp (acc[4] unused when nj==4)

  float acc[5] = {0.f, 0.f, 0.f, 0.f, 0.f};

#pragma unroll 1
  for (int cg = 0; cg < 64; cg += 4) {
    int bufi = (cg >> 2) & 1;
#pragma unroll
    for (int i = 0; i < 4; ++i)
      if (sok[i]) halo[bufi][tid + (i << 9)] = stg[i];
    if (cg < 60) {
#pragma unroll
      for (int i = 0; i < 4; ++i)
        stg[i] = svld[i] ? xb0[((size_t)(cg + 4 + spl[i]) << 14) + sofs[i]]
                         : 0.f;
    }
    BAR_LGKM();
    const float* hb = halo[bufi];
#pragma unroll
    for (int p = 0; p < 4; ++p) {
      const float* wc = wofft + (cg + p) * 162;
      const float* base = hb + p * 390 + px;
#pragma unroll
      for (int t = 0; t < 9; ++t) {
        float v = base[(t / 3) * 130 + (t % 3)];
        acc[0] = fmaf(v, wc[t * 18 + jbase], acc[0]);
        acc[1] = fmaf(v, wc[t * 18 + jbase + 1], acc[1]);
        acc[2] = fmaf(v, wc[t * 18 + jbase + 2], acc[2]);
        acc[3] = fmaf(v, wc[t * 18 + jbase + 3], acc[3]);
        acc[4] = fmaf(v, wc[t * 18 + j4], acc[4]);
      }
    }
  }
#pragma unroll
  for (int i = 0; i < 5; ++i) {
    if (i < nj) {
      int j = jbase + i;
      off[((size_t)(b * 18 + j) << 14) + (h << 7) + px] = acc[i] + boff[j];
    }
  }
}

// ---------------- fused deformable sample + einsum + BN + ReLU --------------
// R13 structure (y-sorted gathers — the TA win) + px-major sbuf [px*12+k]:
// the einsum's 9 stride-64 ds_read_b32 become 2x ds_read_b128 + 1x b32
// (LDS-read pipe was ~2090 of the 3590 cyc/c wall, co-dominant with VALU).
// FMA order per-oi unchanged (k ascending) -> results identical.
__global__ __launch_bounds__(512, 8) void dcn_main_kernel(
    const float* __restrict__ xin, const float* __restrict__ off,
    const float* __restrict__ wt, const float* __restrict__ bn,
    float* __restrict__ out) {
  __shared__ float prm[576 * 6];   // per-slot {q0,q1,q2,q3, ra, rb}
  __shared__ int sortmap[576];
  __shared__ int hist[32];
  __shared__ __align__(16) float sbuf[2][768];   // [buf][px*12 + k]
  int tid = threadIdx.x;
  int pxl = tid & 63;
  int og = tid >> 6;
  int ogu = __builtin_amdgcn_readfirstlane(og);
  int p0 = swz_block(blockIdx.x) * 64;
  int b = p0 >> 14, hw0 = p0 & 16383;
  int h = hw0 >> 7, w0 = hw0 & 127;
  const float* xb = xin + ((size_t)b << 20);

  bool act1 = (tid & 7) == 0;      // this thread also owns slot s1
  int s1 = 512 + (tid >> 3);

  if (tid < 32) hist[tid] = 0;

  // ---- compute per-slot params (folded-coeff path), store to LDS ----
  int bkt[2];
#pragma unroll
  for (int j = 0; j < 2; ++j) {
    bool a = (j == 0) || act1;
    int s = (j == 0) ? tid : s1;
    int k = s >> 6;                // 0..8
    int pxs = s & 63;
    int hw = hw0 + pxs;
    float dy = a ? off[((size_t)(b * 18 + 2 * k) << 14) + hw] : 0.f;
    float dx = a ? off[((size_t)(b * 18 + 2 * k + 1) << 14) + hw] : 0.f;
    float py = (float)(h + k / 3 - 1) + dy;
    float pxf = (float)(w0 + pxs + k % 3 - 1) + dx;
    float y0f = floorf(py), x0f = floorf(pxf);
    float wy1 = py - y0f, wx1 = pxf - x0f;
    float wy0 = 1.f - wy1, wx0 = 1.f - wx1;
    int y0 = (int)y0f, x0 = (int)x0f;
    int y1 = y0 + 1, x1 = x0 + 1;
    bool vy0 = (y0 >= 0) && (y0 <= 127);
    bool vy1 = (y1 >= 0) && (y1 <= 127);
    bool vx0 = (x0 >= 0) && (x0 <= 127);
    bool vx1 = (x1 >= 0) && (x1 <= 127);
    float pw0 = (vy0 && vx0) ? wy0 * wx0 : 0.f;
    float pw1 = (vy0 && vx1) ? wy0 * wx1 : 0.f;
    float pw2 = (vy1 && vx0) ? wy1 * wx0 : 0.f;
    float pw3 = (vy1 && vx1) ? wy1 * wx1 : 0.f;
    int y0c = min(max(y0, 0), 127), y1c = min(max(y1, 0), 127);
    int xb2 = min(max(x0, 0), 126);
    bool se0 = (x0 == xb2);
    bool se1 = (x0 + 1 == xb2);
    float f0 = (se0 ? pw0 : 0.f) + (se1 ? pw1 : 0.f);
    float f1 = (se0 ? 0.f : pw0) + (se1 ? 0.f : pw1);
    float f2 = (se0 ? pw2 : 0.f) + (se1 ? pw3 : 0.f);
    float f3 = (se0 ? 0.f : pw2) + (se1 ? 0.f : pw3);
    if (a) {
      float* pp = &prm[s * 6];
      pp[0] = f0; pp[1] = f1; pp[2] = f2; pp[3] = f3;
      ((int*)pp)[4] = (y0c << 7) + xb2;
      ((int*)pp)[5] = (y1c << 7) + xb2;
    }
    bkt[j] = min(max(y0 - (h - 10), 0), 20);
  }
  __syncthreads();
  // ---- counting sort by y-bucket ----
  atomicAdd(&hist[bkt[0]], 1);
  if (act1) atomicAdd(&hist[bkt[1]], 1);
  __syncthreads();
  if (tid == 0) {
    int run = 0;
#pragma unroll 1
    for (int i = 0; i <= 20; ++i) { int t = hist[i]; hist[i] = run; run += t; }
  }
  __syncthreads();
  {
    int r0 = atomicAdd(&hist[bkt[0]], 1);
    sortmap[r0] = tid;
    if (act1) {
      int r1 = atomicAdd(&hist[bkt[1]], 1);
      sortmap[r1] = s1;
    }
  }
  __syncthreads();

  // ---- load working params for sorted slots ----
  int ws0 = sortmap[tid];
  int ws1 = act1 ? sortmap[512 + (tid >> 3)] : 0;
  int wsa0 = (ws0 & 63) * 12 + (ws0 >> 6);   // px-major sbuf address
  int wsa1 = (ws1 & 63) * 12 + (ws1 >> 6);
  float q[2][4];
  const float* pa[2];
  const float* pb[2];
  {
    const float* pp = &prm[ws0 * 6];
    q[0][0] = pp[0]; q[0][1] = pp[1]; q[0][2] = pp[2]; q[0][3] = pp[3];
    pa[0] = xb + ((const int*)pp)[4];
    pb[0] = xb + ((const int*)pp)[5];
  }
  if (act1) {
    const float* pp = &prm[ws1 * 6];
    q[1][0] = pp[0]; q[1][1] = pp[1]; q[1][2] = pp[2]; q[1][3] = pp[3];
    pa[1] = xb + ((const int*)pp)[4];
    pb[1] = xb + ((const int*)pp)[5];
  } else {
    q[1][0] = q[1][1] = q[1][2] = q[1][3] = 0.f;
    pa[1] = xb; pb[1] = xb;
  }

  // prologue: taps for c=0; advance pointers to plane 1
  float2 t0a = *(const float2*)pa[0];
  float2 t1a = *(const float2*)pb[0];
  float2 t0b = act1 ? *(const float2*)pa[1] : make_float2(0.f, 0.f);
  float2 t1b = act1 ? *(const float2*)pb[1] : make_float2(0.f, 0.f);
  pa[0] += 16384; pb[0] += 16384; pa[1] += 16384; pb[1] += 16384;

  float acc[8];
#pragma unroll
  for (int oi = 0; oi < 8; ++oi) acc[oi] = 0.f;

#pragma unroll 1
  for (int c = 0; c < 64; ++c) {
    // blend + scatter to sbuf at px-major address (einsum reads contiguous)
    sbuf[c & 1][wsa0] = fmaf(q[0][0], t0a.x,
                        fmaf(q[0][1], t0a.y,
                        fmaf(q[0][2], t1a.x, q[0][3] * t1a.y)));
    if (act1) {
      sbuf[c & 1][wsa1] = fmaf(q[1][0], t0b.x,
                          fmaf(q[1][1], t0b.y,
                          fmaf(q[1][2], t1b.x, q[1][3] * t1b.y)));
    }
    // prefetch taps for c+1 (in flight across the lgkm barrier)
    if (c < 63) {
      t0a = *(const float2*)pa[0];
      t1a = *(const float2*)pb[0];
      if (act1) {
        t0b = *(const float2*)pa[1];
        t1b = *(const float2*)pb[1];
      }
      pa[0] += 16384; pb[0] += 16384; pa[1] += 16384; pb[1] += 16384;
    }
    BAR_LGKM();
    const float* wc = wt + (c * 8 + ogu) * 72;   // [c][og][k][8], s_load
    const float* sb = &sbuf[c & 1][pxl * 12];
    float4 sA = *(const float4*)sb;            // k 0..3
    float4 sB = *(const float4*)(sb + 4);      // k 4..7
    float s8 = sb[8];                          // k 8
    float sv[9] = {sA.x, sA.y, sA.z, sA.w, sB.x, sB.y, sB.z, sB.w, s8};
#pragma unroll
    for (int k = 0; k < 9; ++k) {
#pragma unroll
      for (int oi = 0; oi < 8; ++oi)
        acc[oi] = fmaf(sv[k], wc[k * 8 + oi], acc[oi]);
    }
  }

#pragma unroll
  for (int oi = 0; oi < 8; ++oi) {
    int o = ogu * 8 + oi;
    float rres = fmaf(acc[oi], bn[o], bn[64 + o]);
    out[((size_t)(b * 64 + o) << 14) + hw0 + pxl] = fmaxf(rres, 0.f);
  }
}

extern "C" void kernel_launch(void* const* d_in, const int* in_sizes, int n_in,
                              void* d_out, int out_size, void* d_ws, size_t ws_size,
                              hipStream_t stream) {
  const float* x      = (const float*)d_in[0];
  const float* w_off1 = (const float*)d_in[1];
  const float* b_off1 = (const float*)d_in[2];
  const float* w1     = (const float*)d_in[3];
  const float* g1     = (const float*)d_in[4];
  const float* be1    = (const float*)d_in[5];
  const float* m1     = (const float*)d_in[6];
  const float* v1     = (const float*)d_in[7];
  const float* w_off2 = (const float*)d_in[8];
  const float* b_off2 = (const float*)d_in[9];
  const float* w2     = (const float*)d_in[10];
  const float* g2     = (const float*)d_in[11];
  const float* be2    = (const float*)d_in[12];
  const float* m2     = (const float*)d_in[13];
  const float* v2     = (const float*)d_in[14];
  float* out = (float*)d_out;

  float* ws   = (float*)d_ws;
  float* wt1  = ws;
  float* wt2  = ws + 36864;
  float* wo1  = ws + 73728;
  float* wo2  = ws + 84096;
  float* bn1  = ws + 94464;
  float* bn2  = ws + 94592;
  float* offb = ws + 94720;
  float* hbuf = ws + 1274368;

  prep_kernel<<<370, 256, 0, stream>>>(w1, w2, w_off1, w_off2,
                                       g1, be1, m1, v1, g2, be2, m2, v2, ws);

  conv_off_kernel<<<512, 512, 0, stream>>>(x, wo1, b_off1, offb);
  dcn_main_kernel<<<1024, 512, 0, stream>>>(x, offb, wt1, bn1, hbuf);

  conv_off_kernel<<<512, 512, 0, stream>>>(hbuf, wo2, b_off2, offb);
  dcn_main_kernel<<<1024, 512, 0, stream>>>(hbuf, offb, wt2, bn2, out);
}